// Round 8
// baseline (3976.424 us; speedup 1.0000x reference)
//
#include <hip/hip_runtime.h>
#include <stdint.h>

typedef short short8 __attribute__((ext_vector_type(8)));
typedef float f32x4 __attribute__((ext_vector_type(4)));
typedef float f32x2 __attribute__((ext_vector_type(2)));
typedef unsigned long long u64;

#define TSEQ   128
#define BATCH  64
#define DIM    512
#define HID    1024
#define G3     3072
#define MROWS  (TSEQ * BATCH)   // 8192
#define NB     32               // gru participants
#define GRID_GRU 256            // launched; non-participants exit after election
#define HB     32               // hidden units per participant

// per-gru barrier region layout (16 KB each, 2 regions)
#define FLAGS_OFF 0       // 32 x 64B
#define PROBE_OFF 4096    // 32 x 64B
#define OK_OFF    8192    // 32 x 64B
#define CTL_OFF   12288   // [0..7] arrivals, [8] chosen+1

__device__ __forceinline__ unsigned short f2bf(float f) {
  union { float f; unsigned u; } v; v.f = f;
  unsigned u = v.u;
  return (unsigned short)((u + 0x7FFFu + ((u >> 16) & 1u)) >> 16);
}

__device__ __forceinline__ short8 pack8(f32x4 a, f32x4 b) {
  short8 r;
  r[0] = (short)f2bf(a.x); r[1] = (short)f2bf(a.y);
  r[2] = (short)f2bf(a.z); r[3] = (short)f2bf(a.w);
  r[4] = (short)f2bf(b.x); r[5] = (short)f2bf(b.y);
  r[6] = (short)f2bf(b.z); r[7] = (short)f2bf(b.w);
  return r;
}

__device__ __forceinline__ u64 packbf4(float a, float b, float c, float d) {
  return (u64)f2bf(a) | ((u64)f2bf(b) << 16) | ((u64)f2bf(c) << 32) | ((u64)f2bf(d) << 48);
}

__device__ __forceinline__ float sigm(float x) { return 1.0f / (1.0f + __expf(-x)); }
__device__ __forceinline__ float tanh_fast(float x) { return 2.0f / (1.0f + __expf(-2.0f * x)) - 1.0f; }

// ---------------- prep: gather emb rows + convert Wih to bf16 + zero barrier regions ----------------
__global__ __launch_bounds__(256) void prep_kernel(
    const int* __restrict__ ids, const float* __restrict__ emb,
    const float* __restrict__ wih, unsigned short* __restrict__ X,
    unsigned short* __restrict__ Wb, unsigned int* bars)
{
  int row = blockIdx.x;
  int tid = threadIdx.x;
  const float* srcp;
  unsigned short* dst;
  if (row < MROWS) {
    srcp = emb + (long)ids[row] * DIM;
    dst  = X + (long)row * DIM;
  } else {
    int wr = row - MROWS;
    srcp = wih + (long)wr * DIM;
    dst  = Wb + (long)wr * DIM;
  }
  int d = tid * 2;
  f32x2 v = *(const f32x2*)(srcp + d);
  unsigned pk = (unsigned)f2bf(v.x) | ((unsigned)f2bf(v.y) << 16);
  *(unsigned*)(dst + d) = pk;
  if (bars != nullptr && row == 0) {          // zero both 16KB regions
    #pragma unroll
    for (int k = 0; k < 8; ++k) ((f32x4*)bars)[k * 256 + tid] = (f32x4){};
  }
}

// ---------------- xW GEMM: C[m][n] = sum_k X[m][k]*W[n][k] + bih[n] ----------------
#define BM 128
#define BN 128
#define BK 32

__global__ __launch_bounds__(256) void xw_gemm(
    const unsigned short* __restrict__ X,   // [8192][512] bf16
    const unsigned short* __restrict__ W,   // [3072][512] bf16
    const float* __restrict__ bih,          // [3072]
    float* __restrict__ out)                // [8192][3072] f32
{
  __shared__ unsigned short As[BM * BK];
  __shared__ unsigned short Bs[BN * BK];
  int tid = threadIdx.x;
  int w = tid >> 6, l = tid & 63;
  int m0 = blockIdx.y * BM;
  int n0 = blockIdx.x * BN;
  int wr = w >> 1, wc = w & 1;

  int sr = tid >> 2, skq = tid & 3;
  int sr2 = sr + 64;
  int sgk  = (skq - (sr  >> 1)) & 3;
  int sgk2 = (skq - (sr2 >> 1)) & 3;
  const unsigned short* gA0 = X + (long)(m0 + sr ) * DIM + sgk  * 8;
  const unsigned short* gA1 = X + (long)(m0 + sr2) * DIM + sgk2 * 8;
  const unsigned short* gB0 = W + (long)(n0 + sr ) * DIM + sgk  * 8;
  const unsigned short* gB1 = W + (long)(n0 + sr2) * DIM + sgk2 * 8;
  unsigned short* lA0 = As + sr  * BK + skq * 8;
  unsigned short* lA1 = As + sr2 * BK + skq * 8;
  unsigned short* lB0 = Bs + sr  * BK + skq * 8;
  unsigned short* lB1 = Bs + sr2 * BK + skq * 8;

  f32x4 acc[4][4];
  #pragma unroll
  for (int mt = 0; mt < 4; ++mt)
    #pragma unroll
    for (int nt = 0; nt < 4; ++nt) acc[mt][nt] = (f32x4){};

  short8 va0 = *(const short8*)(gA0);
  short8 va1 = *(const short8*)(gA1);
  short8 vb0 = *(const short8*)(gB0);
  short8 vb1 = *(const short8*)(gB1);

  int fr = l & 15, fk = l >> 4;
  for (int kt = 0; kt < DIM / BK; ++kt) {
    __syncthreads();
    *(short8*)lA0 = va0; *(short8*)lA1 = va1;
    *(short8*)lB0 = vb0; *(short8*)lB1 = vb1;
    __syncthreads();
    if (kt + 1 < DIM / BK) {
      int ko = (kt + 1) * BK;
      va0 = *(const short8*)(gA0 + ko);
      va1 = *(const short8*)(gA1 + ko);
      vb0 = *(const short8*)(gB0 + ko);
      vb1 = *(const short8*)(gB1 + ko);
    }
    short8 af[4], bf[4];
    #pragma unroll
    for (int mt = 0; mt < 4; ++mt) {
      int r = wr * 64 + mt * 16 + fr;
      int slot = ((r >> 1) + fk) & 3;
      af[mt] = *(const short8*)(As + r * BK + slot * 8);
    }
    #pragma unroll
    for (int nt = 0; nt < 4; ++nt) {
      int r = wc * 64 + nt * 16 + fr;
      int slot = ((r >> 1) + fk) & 3;
      bf[nt] = *(const short8*)(Bs + r * BK + slot * 8);
    }
    #pragma unroll
    for (int mt = 0; mt < 4; ++mt)
      #pragma unroll
      for (int nt = 0; nt < 4; ++nt)
        acc[mt][nt] = __builtin_amdgcn_mfma_f32_16x16x32_bf16(af[mt], bf[nt], acc[mt][nt], 0, 0, 0);
  }

  #pragma unroll
  for (int nt = 0; nt < 4; ++nt) {
    int n = n0 + wc * 64 + nt * 16 + fr;
    float bias = bih[n];
    #pragma unroll
    for (int mt = 0; mt < 4; ++mt) {
      int mbase = m0 + wr * 64 + mt * 16 + fk * 4;
      #pragma unroll
      for (int r = 0; r < 4; ++r)
        out[(long)(mbase + r) * G3 + n] = acc[mt][nt][r] + bias;
    }
  }
}

// ---------------- persistent masked GRU with verified single-XCD fast path ----------------
#define MF(a, b, c) __builtin_amdgcn_mfma_f32_16x16x32_bf16(a, b, c, 0, 0, 0)

#define ISSUE(ss, kk) do { \
  asm volatile("global_load_dwordx4 %0, %1, off offset:%2 sc0" \
               : "=v"(bv[ss][0]) : "v"(ad0), "i"((kk) * 64) : "memory"); \
  asm volatile("global_load_dwordx4 %0, %1, off offset:%2 sc0" \
               : "=v"(bv[ss][1]) : "v"(ad1), "i"((kk) * 64) : "memory"); \
  asm volatile("global_load_dwordx4 %0, %1, off offset:%2 sc0" \
               : "=v"(bv[ss][2]) : "v"(ad2), "i"((kk) * 64) : "memory"); \
  asm volatile("global_load_dwordx4 %0, %1, off offset:%2 sc0" \
               : "=v"(bv[ss][3]) : "v"(ad3), "i"((kk) * 64) : "memory"); \
} while (0)

#define MF6(kk, ss, nt) \
  acc[0][nt] = MF(areg[0][kk], bv[ss][nt], acc[0][nt]); \
  acc[1][nt] = MF(areg[1][kk], bv[ss][nt], acc[1][nt]); \
  acc[2][nt] = MF(areg[2][kk], bv[ss][nt], acc[2][nt]); \
  acc[3][nt] = MF(areg[3][kk], bv[ss][nt], acc[3][nt]); \
  acc[4][nt] = MF(areg[4][kk], bv[ss][nt], acc[4][nt]); \
  acc[5][nt] = MF(areg[5][kk], bv[ss][nt], acc[5][nt]);

#define CONS(kk, ss, wn) do { \
  asm volatile("s_waitcnt vmcnt(" #wn ")" ::: "memory"); \
  __builtin_amdgcn_sched_barrier(0); \
  MF6(kk, ss, 0) MF6(kk, ss, 1) MF6(kk, ss, 2) MF6(kk, ss, 3) \
} while (0)

#define CONSI(kk, ss, wn, nk) do { CONS(kk, ss, wn); ISSUE(ss, nk); } while (0)

#define LOAD_XW(tt) do { \
    const float* xp_ = xw + ((size_t)(tt) * BATCH + gb) * G3 + U0 + j0; \
    xrv[0] = *(const f32x4*)(xp_);            xrv[1] = *(const f32x4*)(xp_ + 4); \
    xzv[0] = *(const f32x4*)(xp_ + HID);      xzv[1] = *(const f32x4*)(xp_ + HID + 4); \
    xnv[0] = *(const f32x4*)(xp_ + 2 * HID);  xnv[1] = *(const f32x4*)(xp_ + 2 * HID + 4); \
  } while (0)

template<bool FAST>
__device__ __forceinline__ void st_h16(uint64_t a, f32x4 v) {
  if constexpr (FAST)
    asm volatile("global_store_dwordx4 %0, %1, off sc0" :: "v"(a), "v"(v) : "memory");
  else
    asm volatile("global_store_dwordx4 %0, %1, off sc0 sc1" :: "v"(a), "v"(v) : "memory");
}

template<bool FAST>
__device__ __forceinline__ void bar_arrive(unsigned* flags, unsigned rank, unsigned gen, int tid) {
  asm volatile("s_waitcnt vmcnt(0)" ::: "memory");
  __syncthreads();
  if (tid == 0) {
    uint64_t fa = (uint64_t)(flags + (rank << 4));
    if constexpr (FAST)
      asm volatile("global_store_dword %0, %1, off sc0" :: "v"(fa), "v"(gen) : "memory");
    else
      asm volatile("global_store_dword %0, %1, off sc0 sc1" :: "v"(fa), "v"(gen) : "memory");
  }
}

template<bool FAST, bool INV>
__device__ __forceinline__ void bar_wait(unsigned* flags, unsigned gen, int tid) {
  if (tid < NB) {
    unsigned v;
    uint64_t pa = (uint64_t)(flags + (tid << 4));
    do {
      if constexpr (FAST)
        asm volatile("global_load_dword %0, %1, off sc0" : "=v"(v) : "v"(pa) : "memory");
      else
        asm volatile("global_load_dword %0, %1, off sc0 sc1" : "=v"(v) : "v"(pa) : "memory");
      asm volatile("s_waitcnt vmcnt(0)" ::: "memory");
    } while (__any(v < gen));
  }
  __syncthreads();
  if constexpr (INV) asm volatile("buffer_inv sc1" ::: "memory");
}

template<bool FAST>
__device__ __forceinline__ void run_gru(
    const short8 (&areg)[6][8], float (&h)[8],
    const float* __restrict__ xw, u64* __restrict__ hbf,
    unsigned* __restrict__ flags, float* __restrict__ hf32,
    float (*red2)[64][100], float (*bb)[32],
    int tid, int w, int fr, int fk, int gb, int j0,
    unsigned rank, int U0, size_t hoff, int len_b, int T)
{
  f32x4 xrv[2], xzv[2], xnv[2];

  // publish h(0) into buffer 0, entry barrier gen 2 (gen 1 was the probe phase)
  {
    union { u64 q[2]; f32x4 v4; } pk;
    pk.q[0] = packbf4(h[0], h[1], h[2], h[3]);
    pk.q[1] = packbf4(h[4], h[5], h[6], h[7]);
    st_h16<FAST>((uint64_t)(hbf + hoff), pk.v4);
    bar_arrive<FAST>(flags, rank, 2u, tid);
    LOAD_XW(0);
    bar_wait<FAST, !FAST>(flags, 2u, tid);
  }

  for (int t = 0; t < T; ++t) {
    asm volatile("s_waitcnt vmcnt(0)" ::: "memory");

    const char* hbase = (const char*)hbf + (size_t)(t & 1) * (BATCH * (HID / 4) * 8);
    uint64_t ad0 = (uint64_t)(hbase + (size_t)(fr) * 2048 + w * 512 + fk * 16);
    uint64_t ad1 = ad0 + 16 * 2048;
    uint64_t ad2 = ad0 + 32 * 2048;
    uint64_t ad3 = ad0 + 48 * 2048;

    f32x4 acc[6][4];
    #pragma unroll
    for (int mt = 0; mt < 6; ++mt)
      #pragma unroll
      for (int nt = 0; nt < 4; ++nt) acc[mt][nt] = (f32x4){};

    short8 bv[6][4];
    ISSUE(0, 0); ISSUE(1, 1); ISSUE(2, 2); ISSUE(3, 3); ISSUE(4, 4); ISSUE(5, 5);
    CONSI(0, 0, 20, 6);
    CONSI(1, 1, 20, 7);
    CONS(2, 2, 20);
    CONS(3, 3, 16);
    CONS(4, 4, 12);
    CONS(5, 5, 8);
    CONS(6, 0, 4);
    CONS(7, 1, 0);

    #pragma unroll
    for (int mt = 0; mt < 6; ++mt)
      #pragma unroll
      for (int nt = 0; nt < 4; ++nt)
        *(f32x4*)&red2[w][nt * 16 + fr][mt * 16 + fk * 4] = acc[mt][nt];
    __syncthreads();

    #define RD4(s, row) (*(const f32x4*)&red2[s][gb][row])
    f32x4 sr_[2], sz_[2], sn_[2];
    #pragma unroll
    for (int hh = 0; hh < 2; ++hh) {
      const int rbase = j0 + hh * 4;
      sr_[hh] = RD4(0, rbase)      + RD4(1, rbase)      + RD4(2, rbase)      + RD4(3, rbase)      + *(const f32x4*)&bb[0][rbase];
      sz_[hh] = RD4(0, 32 + rbase) + RD4(1, 32 + rbase) + RD4(2, 32 + rbase) + RD4(3, 32 + rbase) + *(const f32x4*)&bb[1][rbase];
      sn_[hh] = RD4(0, 64 + rbase) + RD4(1, 64 + rbase) + RD4(2, 64 + rbase) + RD4(3, 64 + rbase) + *(const f32x4*)&bb[2][rbase];
    }

    const int upd = (t < len_b);
    #pragma unroll
    for (int j = 0; j < 8; ++j) {
      float rr = sigm(xrv[j >> 2][j & 3] + sr_[j >> 2][j & 3]);
      float zz = sigm(xzv[j >> 2][j & 3] + sz_[j >> 2][j & 3]);
      float nn = tanh_fast(xnv[j >> 2][j & 3] + rr * sn_[j >> 2][j & 3]);
      float cc = (1.0f - zz) * nn + zz * h[j];
      h[j] = upd ? cc : h[j];
    }

    if (t + 1 < T) {
      union { u64 q[2]; f32x4 v4; } pk;
      pk.q[0] = packbf4(h[0], h[1], h[2], h[3]);
      pk.q[1] = packbf4(h[4], h[5], h[6], h[7]);
      uint64_t hw = (uint64_t)((char*)hbf + (size_t)((t + 1) & 1) * (BATCH * (HID / 4) * 8) + hoff * 8);
      st_h16<FAST>(hw, pk.v4);
      bar_arrive<FAST>(flags, rank, (unsigned)(t + 3), tid);
      LOAD_XW(t + 1);
      bar_wait<FAST, !FAST>(flags, (unsigned)(t + 3), tid);
    }
  }

  #pragma unroll
  for (int j = 0; j < 8; ++j)
    hf32[(size_t)gb * HID + U0 + j0 + j] = h[j];   // kernel-end flush publishes
}

__global__ __launch_bounds__(256, 1) void gru_kernel(
    const float* __restrict__ Whh, const float* __restrict__ bhh,
    const float* __restrict__ xw, const int* __restrict__ lengths,
    u64* __restrict__ hbf, float* __restrict__ hf32,
    unsigned int* __restrict__ bar, int T, int initzero)
{
  const int tid = threadIdx.x;
  const int w = tid >> 6, l = tid & 63;
  const int fr = l & 15, fk = l >> 4;

  unsigned* flags  = (unsigned*)((char*)bar + FLAGS_OFF);
  unsigned* probes = (unsigned*)((char*)bar + PROBE_OFF);
  unsigned* okf    = (unsigned*)((char*)bar + OK_OFF);
  unsigned* ctl    = (unsigned*)((char*)bar + CTL_OFF);

  // ---- election (always terminates: 256 resident blocks over 8 buckets) ----
  __shared__ unsigned sh_rank, sh_ok, sh_fast;
  if (tid == 0) {
    sh_ok = 1u;
    unsigned xcc;
    asm volatile("s_getreg_b32 %0, hwreg(HW_REG_XCC_ID)" : "=s"(xcc));
    xcc &= 7u;
    unsigned r = __hip_atomic_fetch_add(&ctl[xcc], 1u, __ATOMIC_RELAXED, __HIP_MEMORY_SCOPE_AGENT);
    if (r == (unsigned)NB - 1u) {
      unsigned expected = 0u;
      __hip_atomic_compare_exchange_strong(&ctl[8], &expected, xcc + 1u,
          __ATOMIC_RELAXED, __ATOMIC_RELAXED, __HIP_MEMORY_SCOPE_AGENT);
    }
    unsigned c;
    while ((c = __hip_atomic_load(&ctl[8], __ATOMIC_RELAXED, __HIP_MEMORY_SCOPE_AGENT)) == 0u)
      __builtin_amdgcn_s_sleep(2);
    sh_rank = (xcc == c - 1u && r < (unsigned)NB) ? r : 0xFFFFFFFFu;
  }
  __syncthreads();
  const unsigned rank = sh_rank;
  if (rank == 0xFFFFFFFFu) return;
  const int U0 = (int)rank * HB;

  // ---- coherence self-test: sc0 probe + sc1-proven barrier (gen 1, NO inv) ----
  if (tid == 0) {
    unsigned pv = 0xC0DE0000u | rank;
    uint64_t pa = (uint64_t)(probes + (rank << 4));
    asm volatile("global_store_dword %0, %1, off sc0" :: "v"(pa), "v"(pv) : "memory");
  }
  bar_arrive<false>(flags, rank, 1u, tid);
  bar_wait<false, false>(flags, 1u, tid);
  if (tid < NB) {
    unsigned v;
    uint64_t pa = (uint64_t)(probes + (tid << 4));
    asm volatile("global_load_dword %0, %1, off sc0" : "=v"(v) : "v"(pa) : "memory");
    asm volatile("s_waitcnt vmcnt(0)" ::: "memory");
    if (__any(v != (0xC0DE0000u | (unsigned)tid))) { if (tid == 0) sh_ok = 0u; }
  }
  __syncthreads();
  if (tid == 0) {
    unsigned ov = sh_ok + 1u;   // 1 = bad, 2 = good (nonzero marks "written")
    uint64_t oa = (uint64_t)(okf + (rank << 4));
    asm volatile("global_store_dword %0, %1, off sc0 sc1" :: "v"(oa), "v"(ov) : "memory");
  }
  if (tid < NB) {
    unsigned v;
    uint64_t oa = (uint64_t)(okf + (tid << 4));
    do {
      asm volatile("global_load_dword %0, %1, off sc0 sc1" : "=v"(v) : "v"(oa) : "memory");
      asm volatile("s_waitcnt vmcnt(0)" ::: "memory");
    } while (__any(v == 0u));
    if (tid == 0) sh_fast = __all(v == 2u) ? 1u : 0u;
  }
  __syncthreads();
  const bool fast = (sh_fast != 0u);

  // ---- Whh fragments -> registers: wave w = K-quarter w*256..+255, all 96 gate rows ----
  short8 areg[6][8];
  #pragma unroll
  for (int mt = 0; mt < 6; ++mt) {
    const int m = mt * 16 + fr;
    const int gate = m >> 5, u = m & 31;
    const float* wp = Whh + (size_t)(gate * HID + U0 + u) * HID + w * 256 + fk * 8;
    #pragma unroll
    for (int ksl = 0; ksl < 8; ++ksl) {
      f32x4 a0 = *(const f32x4*)(wp + ksl * 32);
      f32x4 a1 = *(const f32x4*)(wp + ksl * 32 + 4);
      areg[mt][ksl] = pack8(a0, a1);
    }
  }

  const int gb = l;
  const int j0 = w * 8;
  const size_t hoff = (size_t)gb * (HID / 4) + (size_t)(U0 + j0) / 4;
  const int len_b = lengths[gb];

  float h[8];
  #pragma unroll
  for (int j = 0; j < 8; ++j)
    h[j] = initzero ? 0.0f : hf32[(size_t)gb * HID + U0 + j0 + j];

  __shared__ float red2[4][64][100];   // 102.4 KB -> 1 block/CU (election pigeonhole needs this)
  __shared__ float bb[3][32];
  if (tid < 96) bb[tid >> 5][tid & 31] = bhh[(tid >> 5) * HID + U0 + (tid & 31)];

  if (fast)
    run_gru<true >(areg, h, xw, hbf, flags, hf32, red2, bb, tid, w, fr, fk, gb, j0, rank, U0, hoff, len_b, T);
  else
    run_gru<false>(areg, h, xw, hbf, flags, hf32, red2, bb, tid, w, fr, fk, gb, j0, rank, U0, hoff, len_b, T);
}

// ---------------- head: logits = tanh(h @ p1^T + b1) @ p2^T + b2 ----------------
__global__ __launch_bounds__(256) void head_kernel(
    const float* __restrict__ hf32, const float* __restrict__ p1W,
    const float* __restrict__ p1b, const float* __restrict__ p2W,
    const float* __restrict__ p2b, float* __restrict__ outp)
{
  int b = blockIdx.x;
  int tid = threadIdx.x;
  __shared__ float hrow[HID];
  __shared__ float red[4][64];
  __shared__ float s1[64];
  for (int d = tid; d < HID; d += 256) hrow[d] = hf32[(long)b * HID + d];
  __syncthreads();
  int j = tid & 63, q = tid >> 6;
  const float* wrow = p1W + (long)j * HID + q * 256;
  float s = 0.0f;
  for (int k = 0; k < 256; ++k) s += hrow[q * 256 + k] * wrow[k];
  red[q][j] = s;
  __syncthreads();
  if (tid < 64) {
    float v = red[0][tid] + red[1][tid] + red[2][tid] + red[3][tid] + p1b[tid];
    s1[tid] = tanh_fast(v);
  }
  __syncthreads();
  if (tid < 2) {
    float a = p2b[tid];
    for (int k = 0; k < 64; ++k) a += s1[k] * p2W[tid * 64 + k];
    outp[b * 2 + tid] = a;
  }
}

// ---------------- launch ----------------
extern "C" void kernel_launch(void* const* d_in, const int* in_sizes, int n_in,
                              void* d_out, int out_size, void* d_ws, size_t ws_size,
                              hipStream_t stream) {
  const int*   tgt_ids = (const int*)d_in[0];
  const int*   tgt_len = (const int*)d_in[1];
  const int*   src_ids = (const int*)d_in[2];
  const int*   src_len = (const int*)d_in[3];
  const float* emb  = (const float*)d_in[6];
  const float* sWih = (const float*)d_in[7];
  const float* sWhh = (const float*)d_in[8];
  const float* sbih = (const float*)d_in[9];
  const float* sbhh = (const float*)d_in[10];
  const float* tWih = (const float*)d_in[11];
  const float* tWhh = (const float*)d_in[12];
  const float* tbih = (const float*)d_in[13];
  const float* tbhh = (const float*)d_in[14];
  const float* p1W  = (const float*)d_in[19];
  const float* p1b  = (const float*)d_in[20];
  const float* p2W  = (const float*)d_in[21];
  const float* p2b  = (const float*)d_in[22];

  char* ws = (char*)d_ws;
  size_t off = 0;
  float* xw = (float*)(ws + off);                   off += (size_t)MROWS * G3 * 4;
  unsigned short* X  = (unsigned short*)(ws + off); off += (size_t)MROWS * DIM * 2;
  unsigned short* Wb = (unsigned short*)(ws + off); off += (size_t)G3 * DIM * 2;
  u64* hbf = (u64*)(ws + off);                      off += 2ull * BATCH * (HID / 4) * 8;
  float* hf32 = (float*)(ws + off);                 off += (size_t)BATCH * HID * 4;
  unsigned int* bars = (unsigned int*)(ws + off);   off += 32768;  // 2 x 16KB regions
  if (ws_size < off) return;

  const int PREP_BLOCKS = MROWS + G3;  // 11264

  // src pipeline
  prep_kernel<<<PREP_BLOCKS, 256, 0, stream>>>(src_ids, emb, sWih, X, Wb, bars);
  xw_gemm<<<dim3(G3 / BN, MROWS / BM), 256, 0, stream>>>(X, Wb, sbih, xw);
  gru_kernel<<<GRID_GRU, 256, 0, stream>>>(sWhh, sbhh, xw, src_len, hbf, hf32, bars, TSEQ, 1);
  // tgt pipeline (h0 = src final hidden in hf32)
  prep_kernel<<<PREP_BLOCKS, 256, 0, stream>>>(tgt_ids, emb, tWih, X, Wb, nullptr);
  xw_gemm<<<dim3(G3 / BN, MROWS / BM), 256, 0, stream>>>(X, Wb, tbih, xw);
  gru_kernel<<<GRID_GRU, 256, 0, stream>>>(tWhh, tbhh, xw, tgt_len, hbf, hf32, bars + 4096, TSEQ, 0);
  // head
  head_kernel<<<BATCH, 256, 0, stream>>>(hf32, p1W, p1b, p2W, p2b, (float*)d_out);
}

// Round 9
// 2399.968 us; speedup vs baseline: 1.6569x; 1.6569x over previous
//
#include <hip/hip_runtime.h>
#include <stdint.h>

typedef short short8 __attribute__((ext_vector_type(8)));
typedef float f32x4 __attribute__((ext_vector_type(4)));
typedef float f32x2 __attribute__((ext_vector_type(2)));
typedef unsigned long long u64;

#define TSEQ   128
#define BATCH  64
#define DIM    512
#define HID    1024
#define G3     3072
#define MROWS  (TSEQ * BATCH)   // 8192
#define NB     32               // gru blocks (spread placement, R5-style)
#define HB     32               // hidden units per block

__device__ __forceinline__ unsigned short f2bf(float f) {
  union { float f; unsigned u; } v; v.f = f;
  unsigned u = v.u;
  return (unsigned short)((u + 0x7FFFu + ((u >> 16) & 1u)) >> 16);
}

__device__ __forceinline__ short8 pack8(f32x4 a, f32x4 b) {
  short8 r;
  r[0] = (short)f2bf(a.x); r[1] = (short)f2bf(a.y);
  r[2] = (short)f2bf(a.z); r[3] = (short)f2bf(a.w);
  r[4] = (short)f2bf(b.x); r[5] = (short)f2bf(b.y);
  r[6] = (short)f2bf(b.z); r[7] = (short)f2bf(b.w);
  return r;
}

__device__ __forceinline__ u64 packbf4(float a, float b, float c, float d) {
  return (u64)f2bf(a) | ((u64)f2bf(b) << 16) | ((u64)f2bf(c) << 32) | ((u64)f2bf(d) << 48);
}

__device__ __forceinline__ float sigm(float x) { return 1.0f / (1.0f + __expf(-x)); }
__device__ __forceinline__ float tanh_fast(float x) { return 2.0f / (1.0f + __expf(-2.0f * x)) - 1.0f; }

// ---------------- prep: gather emb rows + convert Wih to bf16 + zero flag regions ----------------
__global__ __launch_bounds__(256) void prep_kernel(
    const int* __restrict__ ids, const float* __restrict__ emb,
    const float* __restrict__ wih, unsigned short* __restrict__ X,
    unsigned short* __restrict__ Wb, unsigned int* bars)
{
  int row = blockIdx.x;
  int tid = threadIdx.x;
  const float* srcp;
  unsigned short* dst;
  if (row < MROWS) {
    srcp = emb + (long)ids[row] * DIM;
    dst  = X + (long)row * DIM;
  } else {
    int wr = row - MROWS;
    srcp = wih + (long)wr * DIM;
    dst  = Wb + (long)wr * DIM;
  }
  int d = tid * 2;
  f32x2 v = *(const f32x2*)(srcp + d);
  unsigned pk = (unsigned)f2bf(v.x) | ((unsigned)f2bf(v.y) << 16);
  *(unsigned*)(dst + d) = pk;
  if (bars != nullptr && row == 0) {   // zero 16 KB (both gru regions, A+B flags)
    #pragma unroll
    for (int k = 0; k < 4; ++k) ((f32x4*)bars)[k * 256 + tid] = (f32x4){};
  }
}

// ---------------- xW GEMM: C[m][n] = sum_k X[m][k]*W[n][k] + bih[n] ----------------
#define BM 128
#define BN 128
#define BK 32

__global__ __launch_bounds__(256) void xw_gemm(
    const unsigned short* __restrict__ X,   // [8192][512] bf16
    const unsigned short* __restrict__ W,   // [3072][512] bf16
    const float* __restrict__ bih,          // [3072]
    float* __restrict__ out)                // [8192][3072] f32
{
  __shared__ unsigned short As[BM * BK];
  __shared__ unsigned short Bs[BN * BK];
  int tid = threadIdx.x;
  int w = tid >> 6, l = tid & 63;
  int m0 = blockIdx.y * BM;
  int n0 = blockIdx.x * BN;
  int wr = w >> 1, wc = w & 1;

  int sr = tid >> 2, skq = tid & 3;
  int sr2 = sr + 64;
  int sgk  = (skq - (sr  >> 1)) & 3;
  int sgk2 = (skq - (sr2 >> 1)) & 3;
  const unsigned short* gA0 = X + (long)(m0 + sr ) * DIM + sgk  * 8;
  const unsigned short* gA1 = X + (long)(m0 + sr2) * DIM + sgk2 * 8;
  const unsigned short* gB0 = W + (long)(n0 + sr ) * DIM + sgk  * 8;
  const unsigned short* gB1 = W + (long)(n0 + sr2) * DIM + sgk2 * 8;
  unsigned short* lA0 = As + sr  * BK + skq * 8;
  unsigned short* lA1 = As + sr2 * BK + skq * 8;
  unsigned short* lB0 = Bs + sr  * BK + skq * 8;
  unsigned short* lB1 = Bs + sr2 * BK + skq * 8;

  f32x4 acc[4][4];
  #pragma unroll
  for (int mt = 0; mt < 4; ++mt)
    #pragma unroll
    for (int nt = 0; nt < 4; ++nt) acc[mt][nt] = (f32x4){};

  short8 va0 = *(const short8*)(gA0);
  short8 va1 = *(const short8*)(gA1);
  short8 vb0 = *(const short8*)(gB0);
  short8 vb1 = *(const short8*)(gB1);

  int fr = l & 15, fk = l >> 4;
  for (int kt = 0; kt < DIM / BK; ++kt) {
    __syncthreads();
    *(short8*)lA0 = va0; *(short8*)lA1 = va1;
    *(short8*)lB0 = vb0; *(short8*)lB1 = vb1;
    __syncthreads();
    if (kt + 1 < DIM / BK) {
      int ko = (kt + 1) * BK;
      va0 = *(const short8*)(gA0 + ko);
      va1 = *(const short8*)(gA1 + ko);
      vb0 = *(const short8*)(gB0 + ko);
      vb1 = *(const short8*)(gB1 + ko);
    }
    short8 af[4], bf[4];
    #pragma unroll
    for (int mt = 0; mt < 4; ++mt) {
      int r = wr * 64 + mt * 16 + fr;
      int slot = ((r >> 1) + fk) & 3;
      af[mt] = *(const short8*)(As + r * BK + slot * 8);
    }
    #pragma unroll
    for (int nt = 0; nt < 4; ++nt) {
      int r = wc * 64 + nt * 16 + fr;
      int slot = ((r >> 1) + fk) & 3;
      bf[nt] = *(const short8*)(Bs + r * BK + slot * 8);
    }
    #pragma unroll
    for (int mt = 0; mt < 4; ++mt)
      #pragma unroll
      for (int nt = 0; nt < 4; ++nt)
        acc[mt][nt] = __builtin_amdgcn_mfma_f32_16x16x32_bf16(af[mt], bf[nt], acc[mt][nt], 0, 0, 0);
  }

  #pragma unroll
  for (int nt = 0; nt < 4; ++nt) {
    int n = n0 + wc * 64 + nt * 16 + fr;
    float bias = bih[n];
    #pragma unroll
    for (int mt = 0; mt < 4; ++mt) {
      int mbase = m0 + wr * 64 + mt * 16 + fk * 4;
      #pragma unroll
      for (int r = 0; r < 4; ++r)
        out[(long)(mbase + r) * G3 + n] = acc[mt][nt][r] + bias;
    }
  }
}

// ---------------- persistent masked GRU — two half-batch phases per step ----------------
// Phase A = batches 0..31, phase B = 32..63, independent flag sets. While B
// computes, A's h-stores/flags propagate through the IF (and vice versa), so
// each barrier wait is mostly covered by the other phase's compute.
// Coherence = R4-proven: h stores/loads sc0sc1 via IF, flags sc0sc1. No inv.
#define MF(a, b, c) __builtin_amdgcn_mfma_f32_16x16x32_bf16(a, b, c, 0, 0, 0)

#define ISSUE2(ss, kk) do { \
  asm volatile("global_load_dwordx4 %0, %1, off offset:%2 sc0 sc1" \
               : "=v"(bv[ss][0]) : "v"(ad0), "i"((kk) * 64) : "memory"); \
  asm volatile("global_load_dwordx4 %0, %1, off offset:%2 sc0 sc1" \
               : "=v"(bv[ss][1]) : "v"(ad1), "i"((kk) * 64) : "memory"); \
} while (0)

#define MF12(kk, ss) \
  acc[0][0] = MF(areg[0][kk], bv[ss][0], acc[0][0]); \
  acc[1][0] = MF(areg[1][kk], bv[ss][0], acc[1][0]); \
  acc[2][0] = MF(areg[2][kk], bv[ss][0], acc[2][0]); \
  acc[3][0] = MF(areg[3][kk], bv[ss][0], acc[3][0]); \
  acc[4][0] = MF(areg[4][kk], bv[ss][0], acc[4][0]); \
  acc[5][0] = MF(areg[5][kk], bv[ss][0], acc[5][0]); \
  acc[0][1] = MF(areg[0][kk], bv[ss][1], acc[0][1]); \
  acc[1][1] = MF(areg[1][kk], bv[ss][1], acc[1][1]); \
  acc[2][1] = MF(areg[2][kk], bv[ss][1], acc[2][1]); \
  acc[3][1] = MF(areg[3][kk], bv[ss][1], acc[3][1]); \
  acc[4][1] = MF(areg[4][kk], bv[ss][1], acc[4][1]); \
  acc[5][1] = MF(areg[5][kk], bv[ss][1], acc[5][1]);

#define CONS2(kk, ss, wn) do { \
  asm volatile("s_waitcnt vmcnt(" #wn ")" ::: "memory"); \
  __builtin_amdgcn_sched_barrier(0); \
  MF12(kk, ss) \
} while (0)

#define CONSI2(kk, ss, wn, nk) do { CONS2(kk, ss, wn); ISSUE2(ss, nk); } while (0)

__device__ __forceinline__ void bar_arrive(unsigned* flags, int rank, unsigned gen, int tid) {
  asm volatile("s_waitcnt vmcnt(0)" ::: "memory");
  __syncthreads();
  if (tid == 0) {
    uint64_t fa = (uint64_t)(flags + (rank << 4));
    asm volatile("global_store_dword %0, %1, off sc0 sc1" :: "v"(fa), "v"(gen) : "memory");
  }
}

__device__ __forceinline__ void bar_wait(unsigned* flags, unsigned gen, int tid) {
  if (tid < NB) {
    unsigned v;
    uint64_t pa = (uint64_t)(flags + (tid << 4));
    do {
      asm volatile("global_load_dword %0, %1, off sc0 sc1" : "=v"(v) : "v"(pa) : "memory");
      asm volatile("s_waitcnt vmcnt(0)" ::: "memory");
    } while (__any(v < gen));
  }
  __syncthreads();
}

__global__ __launch_bounds__(256, 1) void gru_kernel(
    const float* __restrict__ Whh, const float* __restrict__ bhh,
    const float* __restrict__ xw, const int* __restrict__ lengths,
    u64* __restrict__ hbf,            // [2][BATCH][HID/4] u64 (4 bf16 each)
    float* __restrict__ hf32,         // [BATCH][HID]
    unsigned int* __restrict__ bar, int T, int initzero)
{
  const int tid = threadIdx.x;
  const int w = tid >> 6, l = tid & 63;
  const int fr = l & 15, fk = l >> 4;
  const int U0 = blockIdx.x * HB;
  const int rank = blockIdx.x;

  unsigned* barA = bar;            // 32 x 64B
  unsigned* barB = bar + 1024;     // +4KB

  // ---- Whh fragments -> registers: wave w = K-quarter, all 96 gate rows ----
  short8 areg[6][8];
  #pragma unroll
  for (int mt = 0; mt < 6; ++mt) {
    const int m = mt * 16 + fr;
    const int gate = m >> 5, u = m & 31;
    const float* wp = Whh + (size_t)(gate * HID + U0 + u) * HID + w * 256 + fk * 8;
    #pragma unroll
    for (int ksl = 0; ksl < 8; ++ksl) {
      f32x4 a0 = *(const f32x4*)(wp + ksl * 32);
      f32x4 a1 = *(const f32x4*)(wp + ksl * 32 + 4);
      areg[mt][ksl] = pack8(a0, a1);
    }
  }

  // ---- gate ownership: batch (within half) = tid&31, units j0u..j0u+3 ----
  const int gb2 = tid & 31;
  const int j0u = (tid >> 5) * 4;                 // 0,4,..,28
  const int bA = gb2, bB = 32 + gb2;
  const size_t hoffA = (size_t)bA * (HID / 4) + (size_t)(U0 + j0u) / 4;
  const size_t hoffB = (size_t)bB * (HID / 4) + (size_t)(U0 + j0u) / 4;
  const int lenA = lengths[bA], lenB = lengths[bB];

  float hA[4], hB[4];
  #pragma unroll
  for (int j = 0; j < 4; ++j) {
    hA[j] = initzero ? 0.0f : hf32[(size_t)bA * HID + U0 + j0u + j];
    hB[j] = initzero ? 0.0f : hf32[(size_t)bB * HID + U0 + j0u + j];
  }

  __shared__ float red2[4][32][100];   // 51.2 KB, reused by both phases
  __shared__ float bb[3][32];
  if (tid < 96) bb[tid >> 5][tid & 31] = bhh[(tid >> 5) * HID + U0 + (tid & 31)];
  __syncthreads();

  const f32x4 bbr = *(const f32x4*)&bb[0][j0u];
  const f32x4 bbz = *(const f32x4*)&bb[1][j0u];
  const f32x4 bbn = *(const f32x4*)&bb[2][j0u];

  f32x4 xrA, xzA, xnA, xrB, xzB, xnB;
  #define LOAD_XWA(tt) do { \
    const float* xp_ = xw + ((size_t)(tt) * BATCH + bA) * G3 + U0 + j0u; \
    xrA = *(const f32x4*)(xp_); xzA = *(const f32x4*)(xp_ + HID); xnA = *(const f32x4*)(xp_ + 2 * HID); \
  } while (0)
  #define LOAD_XWB(tt) do { \
    const float* xp_ = xw + ((size_t)(tt) * BATCH + bB) * G3 + U0 + j0u; \
    xrB = *(const f32x4*)(xp_); xzB = *(const f32x4*)(xp_ + HID); xnB = *(const f32x4*)(xp_ + 2 * HID); \
  } while (0)

  // ---- publish h(0) both halves into buffer 0, flags gen 1 ----
  {
    u64 pA = packbf4(hA[0], hA[1], hA[2], hA[3]);
    u64 pB = packbf4(hB[0], hB[1], hB[2], hB[3]);
    uint64_t aA = (uint64_t)(hbf + hoffA), aB = (uint64_t)(hbf + hoffB);
    asm volatile("global_store_dwordx2 %0, %1, off sc0 sc1" :: "v"(aA), "v"(pA) : "memory");
    asm volatile("global_store_dwordx2 %0, %1, off sc0 sc1" :: "v"(aB), "v"(pB) : "memory");
    bar_arrive(barA, rank, 1u, tid);
    if (tid == 0) {
      uint64_t fb = (uint64_t)(barB + (rank << 4));
      unsigned g1 = 1u;
      asm volatile("global_store_dword %0, %1, off sc0 sc1" :: "v"(fb), "v"(g1) : "memory");
    }
    LOAD_XWA(0); LOAD_XWB(0);
    bar_wait(barA, 1u, tid);
  }

  for (int t = 0; t < T; ++t) {
    const char* hbase = (const char*)hbf + (size_t)(t & 1) * (BATCH * (HID / 4) * 8);
    char* hnext = (char*)hbf + (size_t)((t + 1) & 1) * (BATCH * (HID / 4) * 8);
    const int tail = (t + 1 < T);

    // ================= phase A (batches 0..31) =================
    {
      asm volatile("s_waitcnt vmcnt(0)" ::: "memory");
      uint64_t ad0 = (uint64_t)(hbase + (size_t)fr * 2048 + w * 512 + fk * 16);
      uint64_t ad1 = ad0 + 16 * 2048;
      f32x4 acc[6][2];
      #pragma unroll
      for (int mt = 0; mt < 6; ++mt) { acc[mt][0] = (f32x4){}; acc[mt][1] = (f32x4){}; }
      short8 bv[6][2];
      ISSUE2(0, 0); ISSUE2(1, 1); ISSUE2(2, 2); ISSUE2(3, 3); ISSUE2(4, 4); ISSUE2(5, 5);
      CONSI2(0, 0, 10, 6); CONSI2(1, 1, 10, 7);
      CONS2(2, 2, 10); CONS2(3, 3, 8); CONS2(4, 4, 6); CONS2(5, 5, 4); CONS2(6, 0, 2); CONS2(7, 1, 0);

      #pragma unroll
      for (int mt = 0; mt < 6; ++mt) {
        *(f32x4*)&red2[w][fr][mt * 16 + fk * 4]      = acc[mt][0];
        *(f32x4*)&red2[w][16 + fr][mt * 16 + fk * 4] = acc[mt][1];
      }
      __syncthreads();
      #define RD4(s, row) (*(const f32x4*)&red2[s][gb2][row])
      f32x4 sr_ = RD4(0, j0u)      + RD4(1, j0u)      + RD4(2, j0u)      + RD4(3, j0u)      + bbr;
      f32x4 sz_ = RD4(0, 32 + j0u) + RD4(1, 32 + j0u) + RD4(2, 32 + j0u) + RD4(3, 32 + j0u) + bbz;
      f32x4 sn_ = RD4(0, 64 + j0u) + RD4(1, 64 + j0u) + RD4(2, 64 + j0u) + RD4(3, 64 + j0u) + bbn;
      const int upd = (t < lenA);
      #pragma unroll
      for (int j = 0; j < 4; ++j) {
        float rr = sigm(xrA[j] + sr_[j]);
        float zz = sigm(xzA[j] + sz_[j]);
        float nn = tanh_fast(xnA[j] + rr * sn_[j]);
        float cc = (1.0f - zz) * nn + zz * hA[j];
        hA[j] = upd ? cc : hA[j];
      }
      __syncthreads();   // red2 reads done before phase B writes
    }
    if (tail) {
      u64 pA = packbf4(hA[0], hA[1], hA[2], hA[3]);
      uint64_t aA = (uint64_t)(hnext + hoffA * 8);
      asm volatile("global_store_dwordx2 %0, %1, off sc0 sc1" :: "v"(aA), "v"(pA) : "memory");
      bar_arrive(barA, rank, (unsigned)(t + 2), tid);
      LOAD_XWA(t + 1);   // propagate under phase B
    }
    bar_wait(barB, (unsigned)(t + 1), tid);   // mostly satisfied already

    // ================= phase B (batches 32..63) =================
    {
      asm volatile("s_waitcnt vmcnt(0)" ::: "memory");
      uint64_t ad0 = (uint64_t)(hbase + (size_t)(32 + fr) * 2048 + w * 512 + fk * 16);
      uint64_t ad1 = ad0 + 16 * 2048;
      f32x4 acc[6][2];
      #pragma unroll
      for (int mt = 0; mt < 6; ++mt) { acc[mt][0] = (f32x4){}; acc[mt][1] = (f32x4){}; }
      short8 bv[6][2];
      ISSUE2(0, 0); ISSUE2(1, 1); ISSUE2(2, 2); ISSUE2(3, 3); ISSUE2(4, 4); ISSUE2(5, 5);
      CONSI2(0, 0, 10, 6); CONSI2(1, 1, 10, 7);
      CONS2(2, 2, 10); CONS2(3, 3, 8); CONS2(4, 4, 6); CONS2(5, 5, 4); CONS2(6, 0, 2); CONS2(7, 1, 0);

      #pragma unroll
      for (int mt = 0; mt < 6; ++mt) {
        *(f32x4*)&red2[w][fr][mt * 16 + fk * 4]      = acc[mt][0];
        *(f32x4*)&red2[w][16 + fr][mt * 16 + fk * 4] = acc[mt][1];
      }
      __syncthreads();
      f32x4 sr_ = RD4(0, j0u)      + RD4(1, j0u)      + RD4(2, j0u)      + RD4(3, j0u)      + bbr;
      f32x4 sz_ = RD4(0, 32 + j0u) + RD4(1, 32 + j0u) + RD4(2, 32 + j0u) + RD4(3, 32 + j0u) + bbz;
      f32x4 sn_ = RD4(0, 64 + j0u) + RD4(1, 64 + j0u) + RD4(2, 64 + j0u) + RD4(3, 64 + j0u) + bbn;
      const int upd = (t < lenB);
      #pragma unroll
      for (int j = 0; j < 4; ++j) {
        float rr = sigm(xrB[j] + sr_[j]);
        float zz = sigm(xzB[j] + sz_[j]);
        float nn = tanh_fast(xnB[j] + rr * sn_[j]);
        float cc = (1.0f - zz) * nn + zz * hB[j];
        hB[j] = upd ? cc : hB[j];
      }
      __syncthreads();
    }
    if (tail) {
      u64 pB = packbf4(hB[0], hB[1], hB[2], hB[3]);
      uint64_t aB = (uint64_t)(hnext + hoffB * 8);
      asm volatile("global_store_dwordx2 %0, %1, off sc0 sc1" :: "v"(aB), "v"(pB) : "memory");
      bar_arrive(barB, rank, (unsigned)(t + 2), tid);
      LOAD_XWB(t + 1);   // propagate under next phase A
      bar_wait(barA, (unsigned)(t + 2), tid);   // mostly satisfied already
    }
  }

  #pragma unroll
  for (int j = 0; j < 4; ++j) {
    hf32[(size_t)bA * HID + U0 + j0u + j] = hA[j];
    hf32[(size_t)bB * HID + U0 + j0u + j] = hB[j];
  }
}

// ---------------- head: logits = tanh(h @ p1^T + b1) @ p2^T + b2 ----------------
__global__ __launch_bounds__(256) void head_kernel(
    const float* __restrict__ hf32, const float* __restrict__ p1W,
    const float* __restrict__ p1b, const float* __restrict__ p2W,
    const float* __restrict__ p2b, float* __restrict__ outp)
{
  int b = blockIdx.x;
  int tid = threadIdx.x;
  __shared__ float hrow[HID];
  __shared__ float red[4][64];
  __shared__ float s1[64];
  for (int d = tid; d < HID; d += 256) hrow[d] = hf32[(long)b * HID + d];
  __syncthreads();
  int j = tid & 63, q = tid >> 6;
  const float* wrow = p1W + (long)j * HID + q * 256;
  float s = 0.0f;
  for (int k = 0; k < 256; ++k) s += hrow[q * 256 + k] * wrow[k];
  red[q][j] = s;
  __syncthreads();
  if (tid < 64) {
    float v = red[0][tid] + red[1][tid] + red[2][tid] + red[3][tid] + p1b[tid];
    s1[tid] = tanh_fast(v);
  }
  __syncthreads();
  if (tid < 2) {
    float a = p2b[tid];
    for (int k = 0; k < 64; ++k) a += s1[k] * p2W[tid * 64 + k];
    outp[b * 2 + tid] = a;
  }
}

// ---------------- launch ----------------
extern "C" void kernel_launch(void* const* d_in, const int* in_sizes, int n_in,
                              void* d_out, int out_size, void* d_ws, size_t ws_size,
                              hipStream_t stream) {
  const int*   tgt_ids = (const int*)d_in[0];
  const int*   tgt_len = (const int*)d_in[1];
  const int*   src_ids = (const int*)d_in[2];
  const int*   src_len = (const int*)d_in[3];
  const float* emb  = (const float*)d_in[6];
  const float* sWih = (const float*)d_in[7];
  const float* sWhh = (const float*)d_in[8];
  const float* sbih = (const float*)d_in[9];
  const float* sbhh = (const float*)d_in[10];
  const float* tWih = (const float*)d_in[11];
  const float* tWhh = (const float*)d_in[12];
  const float* tbih = (const float*)d_in[13];
  const float* tbhh = (const float*)d_in[14];
  const float* p1W  = (const float*)d_in[19];
  const float* p1b  = (const float*)d_in[20];
  const float* p2W  = (const float*)d_in[21];
  const float* p2b  = (const float*)d_in[22];

  char* ws = (char*)d_ws;
  size_t off = 0;
  float* xw = (float*)(ws + off);                   off += (size_t)MROWS * G3 * 4;
  unsigned short* X  = (unsigned short*)(ws + off); off += (size_t)MROWS * DIM * 2;
  unsigned short* Wb = (unsigned short*)(ws + off); off += (size_t)G3 * DIM * 2;
  u64* hbf = (u64*)(ws + off);                      off += 2ull * BATCH * (HID / 4) * 8;
  float* hf32 = (float*)(ws + off);                 off += (size_t)BATCH * HID * 4;
  unsigned int* bars = (unsigned int*)(ws + off);   off += 16384;  // 2 gru regions x 8KB (A+B flags)
  if (ws_size < off) return;

  const int PREP_BLOCKS = MROWS + G3;  // 11264

  // src pipeline
  prep_kernel<<<PREP_BLOCKS, 256, 0, stream>>>(src_ids, emb, sWih, X, Wb, bars);
  xw_gemm<<<dim3(G3 / BN, MROWS / BM), 256, 0, stream>>>(X, Wb, sbih, xw);
  gru_kernel<<<NB, 256, 0, stream>>>(sWhh, sbhh, xw, src_len, hbf, hf32, bars, TSEQ, 1);
  // tgt pipeline (h0 = src final hidden in hf32)
  prep_kernel<<<PREP_BLOCKS, 256, 0, stream>>>(tgt_ids, emb, tWih, X, Wb, nullptr);
  xw_gemm<<<dim3(G3 / BN, MROWS / BM), 256, 0, stream>>>(X, Wb, tbih, xw);
  gru_kernel<<<NB, 256, 0, stream>>>(tWhh, tbhh, xw, tgt_len, hbf, hf32, bars + 2048, TSEQ, 0);
  // head
  head_kernel<<<BATCH, 256, 0, stream>>>(hf32, p1W, p1b, p2W, p2b, (float*)d_out);
}

// Round 10
// 2173.978 us; speedup vs baseline: 1.8291x; 1.1040x over previous
//
#include <hip/hip_runtime.h>
#include <stdint.h>

typedef short short8 __attribute__((ext_vector_type(8)));
typedef float f32x4 __attribute__((ext_vector_type(4)));
typedef float f32x2 __attribute__((ext_vector_type(2)));
typedef unsigned long long u64;

#define TSEQ   128
#define BATCH  64
#define DIM    512
#define HID    1024
#define G3     3072
#define MROWS  (TSEQ * BATCH)   // 8192
#define NB     32               // gru blocks
#define HB     32               // hidden units per block
#define RING   32               // h ring slots (reuse distance 32 + wrap inv)
#define SLOT   (BATCH * (HID / 4) * 8)   // 128 KB per slot

__device__ __forceinline__ unsigned short f2bf(float f) {
  union { float f; unsigned u; } v; v.f = f;
  unsigned u = v.u;
  return (unsigned short)((u + 0x7FFFu + ((u >> 16) & 1u)) >> 16);
}

__device__ __forceinline__ short8 pack8(f32x4 a, f32x4 b) {
  short8 r;
  r[0] = (short)f2bf(a.x); r[1] = (short)f2bf(a.y);
  r[2] = (short)f2bf(a.z); r[3] = (short)f2bf(a.w);
  r[4] = (short)f2bf(b.x); r[5] = (short)f2bf(b.y);
  r[6] = (short)f2bf(b.z); r[7] = (short)f2bf(b.w);
  return r;
}

__device__ __forceinline__ u64 packbf4(float a, float b, float c, float d) {
  return (u64)f2bf(a) | ((u64)f2bf(b) << 16) | ((u64)f2bf(c) << 32) | ((u64)f2bf(d) << 48);
}

__device__ __forceinline__ float sigm(float x) { return 1.0f / (1.0f + __expf(-x)); }
__device__ __forceinline__ float tanh_fast(float x) { return 2.0f / (1.0f + __expf(-2.0f * x)) - 1.0f; }

// ---------------- prep: gather emb rows + convert Wih to bf16 + zero flag regions ----------------
__global__ __launch_bounds__(256) void prep_kernel(
    const int* __restrict__ ids, const float* __restrict__ emb,
    const float* __restrict__ wih, unsigned short* __restrict__ X,
    unsigned short* __restrict__ Wb, unsigned int* bars)
{
  int row = blockIdx.x;
  int tid = threadIdx.x;
  const float* srcp;
  unsigned short* dst;
  if (row < MROWS) {
    srcp = emb + (long)ids[row] * DIM;
    dst  = X + (long)row * DIM;
  } else {
    int wr = row - MROWS;
    srcp = wih + (long)wr * DIM;
    dst  = Wb + (long)wr * DIM;
  }
  int d = tid * 2;
  f32x2 v = *(const f32x2*)(srcp + d);
  unsigned pk = (unsigned)f2bf(v.x) | ((unsigned)f2bf(v.y) << 16);
  *(unsigned*)(dst + d) = pk;
  if (bars != nullptr && row == 0) ((f32x4*)bars)[tid] = (f32x4){};  // zero 4 KB (both flag regions)
}

// ---------------- xW GEMM: C[m][n] = sum_k X[m][k]*W[n][k] + bih[n] ----------------
#define BM 128
#define BN 128
#define BK 32

__global__ __launch_bounds__(256) void xw_gemm(
    const unsigned short* __restrict__ X,   // [8192][512] bf16
    const unsigned short* __restrict__ W,   // [3072][512] bf16
    const float* __restrict__ bih,          // [3072]
    float* __restrict__ out)                // [8192][3072] f32
{
  __shared__ unsigned short As[BM * BK];
  __shared__ unsigned short Bs[BN * BK];
  int tid = threadIdx.x;
  int w = tid >> 6, l = tid & 63;
  int m0 = blockIdx.y * BM;
  int n0 = blockIdx.x * BN;
  int wr = w >> 1, wc = w & 1;

  int sr = tid >> 2, skq = tid & 3;
  int sr2 = sr + 64;
  int sgk  = (skq - (sr  >> 1)) & 3;
  int sgk2 = (skq - (sr2 >> 1)) & 3;
  const unsigned short* gA0 = X + (long)(m0 + sr ) * DIM + sgk  * 8;
  const unsigned short* gA1 = X + (long)(m0 + sr2) * DIM + sgk2 * 8;
  const unsigned short* gB0 = W + (long)(n0 + sr ) * DIM + sgk  * 8;
  const unsigned short* gB1 = W + (long)(n0 + sr2) * DIM + sgk2 * 8;
  unsigned short* lA0 = As + sr  * BK + skq * 8;
  unsigned short* lA1 = As + sr2 * BK + skq * 8;
  unsigned short* lB0 = Bs + sr  * BK + skq * 8;
  unsigned short* lB1 = Bs + sr2 * BK + skq * 8;

  f32x4 acc[4][4];
  #pragma unroll
  for (int mt = 0; mt < 4; ++mt)
    #pragma unroll
    for (int nt = 0; nt < 4; ++nt) acc[mt][nt] = (f32x4){};

  short8 va0 = *(const short8*)(gA0);
  short8 va1 = *(const short8*)(gA1);
  short8 vb0 = *(const short8*)(gB0);
  short8 vb1 = *(const short8*)(gB1);

  int fr = l & 15, fk = l >> 4;
  for (int kt = 0; kt < DIM / BK; ++kt) {
    __syncthreads();
    *(short8*)lA0 = va0; *(short8*)lA1 = va1;
    *(short8*)lB0 = vb0; *(short8*)lB1 = vb1;
    __syncthreads();
    if (kt + 1 < DIM / BK) {
      int ko = (kt + 1) * BK;
      va0 = *(const short8*)(gA0 + ko);
      va1 = *(const short8*)(gA1 + ko);
      vb0 = *(const short8*)(gB0 + ko);
      vb1 = *(const short8*)(gB1 + ko);
    }
    short8 af[4], bf[4];
    #pragma unroll
    for (int mt = 0; mt < 4; ++mt) {
      int r = wr * 64 + mt * 16 + fr;
      int slot = ((r >> 1) + fk) & 3;
      af[mt] = *(const short8*)(As + r * BK + slot * 8);
    }
    #pragma unroll
    for (int nt = 0; nt < 4; ++nt) {
      int r = wc * 64 + nt * 16 + fr;
      int slot = ((r >> 1) + fk) & 3;
      bf[nt] = *(const short8*)(Bs + r * BK + slot * 8);
    }
    #pragma unroll
    for (int mt = 0; mt < 4; ++mt)
      #pragma unroll
      for (int nt = 0; nt < 4; ++nt)
        acc[mt][nt] = __builtin_amdgcn_mfma_f32_16x16x32_bf16(af[mt], bf[nt], acc[mt][nt], 0, 0, 0);
  }

  #pragma unroll
  for (int nt = 0; nt < 4; ++nt) {
    int n = n0 + wc * 64 + nt * 16 + fr;
    float bias = bih[n];
    #pragma unroll
    for (int mt = 0; mt < 4; ++mt) {
      int mbase = m0 + wr * 64 + mt * 16 + fk * 4;
      #pragma unroll
      for (int r = 0; r < 4; ++r)
        out[(long)(mbase + r) * G3 + n] = acc[mt][nt][r] + bias;
    }
  }
}

// ---------------- persistent masked GRU — step-unique h ring, L2-cached reads ----------------
// R5-proven structure (write-only LDS reduce, RMW-free flag barrier, dedup'd
// 24-deep pipelined loads). Change: h lives in a 32-slot ring so every step's
// addresses are virgin in consumer L2s -> plain sc0 reads hit the shared XCD
// L2 (first block per XCD pulls from IF, the other ~3 hit). One buffer_inv at
// entry + one per 32-step wrap replaces R5's 128 per-step invs.
#define MF(a, b, c) __builtin_amdgcn_mfma_f32_16x16x32_bf16(a, b, c, 0, 0, 0)

#define ISSUE(ss, kk) do { \
  asm volatile("global_load_dwordx4 %0, %1, off offset:%2 sc0" \
               : "=v"(bv[ss][0]) : "v"(ad0), "i"((kk) * 64) : "memory"); \
  asm volatile("global_load_dwordx4 %0, %1, off offset:%2 sc0" \
               : "=v"(bv[ss][1]) : "v"(ad1), "i"((kk) * 64) : "memory"); \
  asm volatile("global_load_dwordx4 %0, %1, off offset:%2 sc0" \
               : "=v"(bv[ss][2]) : "v"(ad2), "i"((kk) * 64) : "memory"); \
  asm volatile("global_load_dwordx4 %0, %1, off offset:%2 sc0" \
               : "=v"(bv[ss][3]) : "v"(ad3), "i"((kk) * 64) : "memory"); \
} while (0)

#define MF6(kk, ss, nt) \
  acc[0][nt] = MF(areg[0][kk], bv[ss][nt], acc[0][nt]); \
  acc[1][nt] = MF(areg[1][kk], bv[ss][nt], acc[1][nt]); \
  acc[2][nt] = MF(areg[2][kk], bv[ss][nt], acc[2][nt]); \
  acc[3][nt] = MF(areg[3][kk], bv[ss][nt], acc[3][nt]); \
  acc[4][nt] = MF(areg[4][kk], bv[ss][nt], acc[4][nt]); \
  acc[5][nt] = MF(areg[5][kk], bv[ss][nt], acc[5][nt]);

#define CONS(kk, ss, wn) do { \
  asm volatile("s_waitcnt vmcnt(" #wn ")" ::: "memory"); \
  __builtin_amdgcn_sched_barrier(0); \
  MF6(kk, ss, 0) MF6(kk, ss, 1) MF6(kk, ss, 2) MF6(kk, ss, 3) \
} while (0)

#define CONSI(kk, ss, wn, nk) do { CONS(kk, ss, wn); ISSUE(ss, nk); } while (0)

// arrive: h stores already issued; drain, block-sync, publish generation flag
#define BARRIER_ARRIVE(tgtv) do { \
  asm volatile("s_waitcnt vmcnt(0)" ::: "memory"); \
  __syncthreads(); \
  if (tid == 0) { \
    unsigned fv_ = (unsigned)(tgtv); \
    uint64_t fa_ = (uint64_t)(bar + (blockIdx.x << 4)); \
    asm volatile("global_store_dword %0, %1, off sc0 sc1" :: "v"(fa_), "v"(fv_) : "memory"); \
  } \
} while (0)

// wait: lanes 0..31 of wave0 poll all 32 flags (uncached, current at IF)
#define BARRIER_WAIT(tgtv) do { \
  if (tid < NB) { \
    unsigned v_; \
    uint64_t pa_ = (uint64_t)(bar + (tid << 4)); \
    do { \
      asm volatile("global_load_dword %0, %1, off sc0 sc1" : "=v"(v_) : "v"(pa_) : "memory"); \
      asm volatile("s_waitcnt vmcnt(0)" ::: "memory"); \
    } while (__any(v_ < (unsigned)(tgtv))); \
  } \
  __syncthreads(); \
} while (0)

__global__ __launch_bounds__(256, 1) void gru_kernel(
    const float* __restrict__ Whh, const float* __restrict__ bhh,
    const float* __restrict__ xw, const int* __restrict__ lengths,
    u64* __restrict__ hbf,            // ring: [RING][BATCH][HID/4] u64
    float* __restrict__ hf32,         // [BATCH][HID]
    unsigned int* __restrict__ bar, int T, int initzero)
{
  const int tid = threadIdx.x;
  const int w = tid >> 6, l = tid & 63;
  const int fr = l & 15, fk = l >> 4;
  const int U0 = blockIdx.x * HB;

  // ---- Whh fragments -> registers: wave w holds ALL 96 gate rows, K-quarter w*256..+255 ----
  short8 areg[6][8];
  #pragma unroll
  for (int mt = 0; mt < 6; ++mt) {
    const int m = mt * 16 + fr;                    // 0..95
    const int gate = m >> 5, u = m & 31;
    const float* wp = Whh + (size_t)(gate * HID + U0 + u) * HID + w * 256 + fk * 8;
    #pragma unroll
    for (int ksl = 0; ksl < 8; ++ksl) {
      f32x4 a0 = *(const f32x4*)(wp + ksl * 32);
      f32x4 a1 = *(const f32x4*)(wp + ksl * 32 + 4);
      areg[mt][ksl] = pack8(a0, a1);
    }
  }

  // ---- gate-phase ownership: batch gb = lane, units j0..j0+7 (j0 = wave*8) ----
  const int gb = l;
  const int j0 = w * 8;
  const size_t hoff = (size_t)gb * (HID / 4) + (size_t)(U0 + j0) / 4;  // u64 units within a slot
  const int len_b = lengths[gb];

  float h[8];
  #pragma unroll
  for (int j = 0; j < 8; ++j)
    h[j] = initzero ? 0.0f : hf32[(size_t)gb * HID + U0 + j0 + j];

  __shared__ float red2[4][64][100];   // 102.4 KB; [k-slice][batch][gate-row(+pad)]
  __shared__ float bb[3][32];          // biases for this block's 32 units x 3 gates
  if (tid < 96) bb[tid >> 5][tid & 31] = bhh[(tid >> 5) * HID + U0 + (tid & 31)];

  f32x4 xrv[2], xzv[2], xnv[2];
  #define LOAD_XW(tt) do { \
    const float* xp_ = xw + ((size_t)(tt) * BATCH + gb) * G3 + U0 + j0; \
    xrv[0] = *(const f32x4*)(xp_);            xrv[1] = *(const f32x4*)(xp_ + 4); \
    xzv[0] = *(const f32x4*)(xp_ + HID);      xzv[1] = *(const f32x4*)(xp_ + HID + 4); \
    xnv[0] = *(const f32x4*)(xp_ + 2 * HID);  xnv[1] = *(const f32x4*)(xp_ + 2 * HID + 4); \
  } while (0)

  // ---- publish h(0) into ring slot 0; entry inv makes all ring lines virgin locally ----
  {
    union { u64 q[2]; f32x4 v4; } pk;
    pk.q[0] = packbf4(h[0], h[1], h[2], h[3]);
    pk.q[1] = packbf4(h[4], h[5], h[6], h[7]);
    uint64_t hw = (uint64_t)(hbf + hoff);
    asm volatile("global_store_dwordx4 %0, %1, off sc0 sc1" :: "v"(hw), "v"(pk.v4) : "memory");
    BARRIER_ARRIVE(1);
    asm volatile("buffer_inv sc1" ::: "memory");   // drop cross-launch/cross-gru stale ring lines
    LOAD_XW(0);
    BARRIER_WAIT(1);
  }

  for (int t = 0; t < T; ++t) {
    // drain xw prefetch / poll loads before manual vmcnt counting
    asm volatile("s_waitcnt vmcnt(0)" ::: "memory");

    const char* hbase = (const char*)hbf + (size_t)(t & (RING - 1)) * SLOT;
    // lane reads batch row (nt*16+fr), bytes [w*512 + ksl*64 + fk*16 .. +16)
    uint64_t ad0 = (uint64_t)(hbase + (size_t)(fr) * 2048 + w * 512 + fk * 16);
    uint64_t ad1 = ad0 + 16 * 2048;
    uint64_t ad2 = ad0 + 32 * 2048;
    uint64_t ad3 = ad0 + 48 * 2048;

    f32x4 acc[6][4];
    #pragma unroll
    for (int mt = 0; mt < 6; ++mt)
      #pragma unroll
      for (int nt = 0; nt < 4; ++nt) acc[mt][nt] = (f32x4){};

    short8 bv[6][4];
    ISSUE(0, 0); ISSUE(1, 1); ISSUE(2, 2); ISSUE(3, 3); ISSUE(4, 4); ISSUE(5, 5);
    CONSI(0, 0, 20, 6);
    CONSI(1, 1, 20, 7);
    CONS(2, 2, 20);
    CONS(3, 3, 16);
    CONS(4, 4, 12);
    CONS(5, 5, 8);
    CONS(6, 0, 4);
    CONS(7, 1, 0);

    // per-wave K-slice -> LDS, write-only, vectorized
    #pragma unroll
    for (int mt = 0; mt < 6; ++mt)
      #pragma unroll
      for (int nt = 0; nt < 4; ++nt)
        *(f32x4*)&red2[w][nt * 16 + fr][mt * 16 + fk * 4] = acc[mt][nt];
    __syncthreads();

    // gates: sum 4 K-slices (vector LDS reads), add bias, update h
    #define RD4(s, row) (*(const f32x4*)&red2[s][gb][row])
    f32x4 sr_[2], sz_[2], sn_[2];
    #pragma unroll
    for (int hh = 0; hh < 2; ++hh) {
      const int rbase = j0 + hh * 4;
      sr_[hh] = RD4(0, rbase)      + RD4(1, rbase)      + RD4(2, rbase)      + RD4(3, rbase)      + *(const f32x4*)&bb[0][rbase];
      sz_[hh] = RD4(0, 32 + rbase) + RD4(1, 32 + rbase) + RD4(2, 32 + rbase) + RD4(3, 32 + rbase) + *(const f32x4*)&bb[1][rbase];
      sn_[hh] = RD4(0, 64 + rbase) + RD4(1, 64 + rbase) + RD4(2, 64 + rbase) + RD4(3, 64 + rbase) + *(const f32x4*)&bb[2][rbase];
    }

    const int upd = (t < len_b);
    #pragma unroll
    for (int j = 0; j < 8; ++j) {
      float rr = sigm(xrv[j >> 2][j & 3] + sr_[j >> 2][j & 3]);
      float zz = sigm(xzv[j >> 2][j & 3] + sz_[j >> 2][j & 3]);
      float nn = tanh_fast(xnv[j >> 2][j & 3] + rr * sn_[j >> 2][j & 3]);
      float cc = (1.0f - zz) * nn + zz * h[j];
      h[j] = upd ? cc : h[j];
    }

    if (t + 1 < T) {
      union { u64 q[2]; f32x4 v4; } pk;
      pk.q[0] = packbf4(h[0], h[1], h[2], h[3]);
      pk.q[1] = packbf4(h[4], h[5], h[6], h[7]);
      uint64_t hw = (uint64_t)((char*)hbf + (size_t)((t + 1) & (RING - 1)) * SLOT + hoff * 8);
      asm volatile("global_store_dwordx4 %0, %1, off sc0 sc1" :: "v"(hw), "v"(pk.v4) : "memory");
      BARRIER_ARRIVE(t + 2);
      LOAD_XW(t + 1);   // prefetch next step's gate inputs under the barrier wait
      BARRIER_WAIT(t + 2);
      if (((t + 1) & (RING - 1)) == 0)               // ring wrap: drop this XCD's
        asm volatile("buffer_inv sc1" ::: "memory"); // 32-step-old ring lines
    }
  }

  #pragma unroll
  for (int j = 0; j < 8; ++j)
    hf32[(size_t)gb * HID + U0 + j0 + j] = h[j];
}

// ---------------- head: logits = tanh(h @ p1^T + b1) @ p2^T + b2 ----------------
__global__ __launch_bounds__(256) void head_kernel(
    const float* __restrict__ hf32, const float* __restrict__ p1W,
    const float* __restrict__ p1b, const float* __restrict__ p2W,
    const float* __restrict__ p2b, float* __restrict__ outp)
{
  int b = blockIdx.x;
  int tid = threadIdx.x;
  __shared__ float hrow[HID];
  __shared__ float red[4][64];
  __shared__ float s1[64];
  for (int d = tid; d < HID; d += 256) hrow[d] = hf32[(long)b * HID + d];
  __syncthreads();
  int j = tid & 63, q = tid >> 6;
  const float* wrow = p1W + (long)j * HID + q * 256;
  float s = 0.0f;
  for (int k = 0; k < 256; ++k) s += hrow[q * 256 + k] * wrow[k];
  red[q][j] = s;
  __syncthreads();
  if (tid < 64) {
    float v = red[0][tid] + red[1][tid] + red[2][tid] + red[3][tid] + p1b[tid];
    s1[tid] = tanh_fast(v);
  }
  __syncthreads();
  if (tid < 2) {
    float a = p2b[tid];
    for (int k = 0; k < 64; ++k) a += s1[k] * p2W[tid * 64 + k];
    outp[b * 2 + tid] = a;
  }
}

// ---------------- launch ----------------
extern "C" void kernel_launch(void* const* d_in, const int* in_sizes, int n_in,
                              void* d_out, int out_size, void* d_ws, size_t ws_size,
                              hipStream_t stream) {
  const int*   tgt_ids = (const int*)d_in[0];
  const int*   tgt_len = (const int*)d_in[1];
  const int*   src_ids = (const int*)d_in[2];
  const int*   src_len = (const int*)d_in[3];
  const float* emb  = (const float*)d_in[6];
  const float* sWih = (const float*)d_in[7];
  const float* sWhh = (const float*)d_in[8];
  const float* sbih = (const float*)d_in[9];
  const float* sbhh = (const float*)d_in[10];
  const float* tWih = (const float*)d_in[11];
  const float* tWhh = (const float*)d_in[12];
  const float* tbih = (const float*)d_in[13];
  const float* tbhh = (const float*)d_in[14];
  const float* p1W  = (const float*)d_in[19];
  const float* p1b  = (const float*)d_in[20];
  const float* p2W  = (const float*)d_in[21];
  const float* p2b  = (const float*)d_in[22];

  char* ws = (char*)d_ws;
  size_t off = 0;
  float* xw = (float*)(ws + off);                   off += (size_t)MROWS * G3 * 4;   // 100.7 MB
  unsigned short* X  = (unsigned short*)(ws + off); off += (size_t)MROWS * DIM * 2;  // 8.4 MB
  unsigned short* Wb = (unsigned short*)(ws + off); off += (size_t)G3 * DIM * 2;     // 3.1 MB
  float* hf32 = (float*)(ws + off);                 off += (size_t)BATCH * HID * 4;
  unsigned int* bars = (unsigned int*)(ws + off);   off += 8192;
  if (ws_size < off) return;
  // h ring (4.2 MB) aliases the X/Wb staging region (11.5 MB): X/Wb are only
  // live between prep and xw_gemm; the ring is only live inside gru_kernel;
  // the two never overlap in time, and each gru's entry buffer_inv drops any
  // stale cached lines from the region's previous use.
  u64* hbf = (u64*)X;

  const int PREP_BLOCKS = MROWS + G3;  // 11264

  // src pipeline
  prep_kernel<<<PREP_BLOCKS, 256, 0, stream>>>(src_ids, emb, sWih, X, Wb, bars);
  xw_gemm<<<dim3(G3 / BN, MROWS / BM), 256, 0, stream>>>(X, Wb, sbih, xw);
  gru_kernel<<<NB, 256, 0, stream>>>(sWhh, sbhh, xw, src_len, hbf, hf32, bars, TSEQ, 1);
  // tgt pipeline (h0 = src final hidden in hf32)
  prep_kernel<<<PREP_BLOCKS, 256, 0, stream>>>(tgt_ids, emb, tWih, X, Wb, nullptr);
  xw_gemm<<<dim3(G3 / BN, MROWS / BM), 256, 0, stream>>>(X, Wb, tbih, xw);
  gru_kernel<<<NB, 256, 0, stream>>>(tWhh, tbhh, xw, tgt_len, hbf, hf32, bars + 512, TSEQ, 0);
  // head
  head_kernel<<<BATCH, 256, 0, stream>>>(hf32, p1W, p1b, p2W, p2b, (float*)d_out);
}

// Round 11
// 2162.838 us; speedup vs baseline: 1.8385x; 1.0052x over previous
//
#include <hip/hip_runtime.h>
#include <stdint.h>

typedef short short8 __attribute__((ext_vector_type(8)));
typedef float f32x4 __attribute__((ext_vector_type(4)));
typedef float f32x2 __attribute__((ext_vector_type(2)));
typedef unsigned long long u64;

#define TSEQ   128
#define BATCH  64
#define DIM    512
#define HID    1024
#define G3     3072
#define MROWS  (TSEQ * BATCH)   // 8192
#define NB     32               // gru blocks
#define HB     32               // hidden units per block
#define RING   32               // h ring slots
#define SLOT   (BATCH * (HID / 4) * 8)   // 128 KB per slot

__device__ __forceinline__ unsigned short f2bf(float f) {
  union { float f; unsigned u; } v; v.f = f;
  unsigned u = v.u;
  return (unsigned short)((u + 0x7FFFu + ((u >> 16) & 1u)) >> 16);
}

__device__ __forceinline__ short8 pack8(f32x4 a, f32x4 b) {
  short8 r;
  r[0] = (short)f2bf(a.x); r[1] = (short)f2bf(a.y);
  r[2] = (short)f2bf(a.z); r[3] = (short)f2bf(a.w);
  r[4] = (short)f2bf(b.x); r[5] = (short)f2bf(b.y);
  r[6] = (short)f2bf(b.z); r[7] = (short)f2bf(b.w);
  return r;
}

__device__ __forceinline__ u64 packbf4(float a, float b, float c, float d) {
  return (u64)f2bf(a) | ((u64)f2bf(b) << 16) | ((u64)f2bf(c) << 32) | ((u64)f2bf(d) << 48);
}

__device__ __forceinline__ float sigm(float x) { return 1.0f / (1.0f + __expf(-x)); }
__device__ __forceinline__ float tanh_fast(float x) { return 2.0f / (1.0f + __expf(-2.0f * x)) - 1.0f; }

// ---------------- prep: gather emb rows + convert Wih to bf16 + zero flag regions ----------------
__global__ __launch_bounds__(256) void prep_kernel(
    const int* __restrict__ ids, const float* __restrict__ emb,
    const float* __restrict__ wih, unsigned short* __restrict__ X,
    unsigned short* __restrict__ Wb, unsigned int* bars)
{
  int row = blockIdx.x;
  int tid = threadIdx.x;
  const float* srcp;
  unsigned short* dst;
  if (row < MROWS) {
    srcp = emb + (long)ids[row] * DIM;
    dst  = X + (long)row * DIM;
  } else {
    int wr = row - MROWS;
    srcp = wih + (long)wr * DIM;
    dst  = Wb + (long)wr * DIM;
  }
  int d = tid * 2;
  f32x2 v = *(const f32x2*)(srcp + d);
  unsigned pk = (unsigned)f2bf(v.x) | ((unsigned)f2bf(v.y) << 16);
  *(unsigned*)(dst + d) = pk;
  if (bars != nullptr && row == 0) ((f32x4*)bars)[tid] = (f32x4){};  // zero 4 KB (both flag regions)
}

// ---------------- xW GEMM: C[m][n] = sum_k X[m][k]*W[n][k] + bih[n] ----------------
#define BM 128
#define BN 128
#define BK 32

__global__ __launch_bounds__(256) void xw_gemm(
    const unsigned short* __restrict__ X,   // [8192][512] bf16
    const unsigned short* __restrict__ W,   // [3072][512] bf16
    const float* __restrict__ bih,          // [3072]
    float* __restrict__ out)                // [8192][3072] f32
{
  __shared__ unsigned short As[BM * BK];
  __shared__ unsigned short Bs[BN * BK];
  int tid = threadIdx.x;
  int w = tid >> 6, l = tid & 63;
  int m0 = blockIdx.y * BM;
  int n0 = blockIdx.x * BN;
  int wr = w >> 1, wc = w & 1;

  int sr = tid >> 2, skq = tid & 3;
  int sr2 = sr + 64;
  int sgk  = (skq - (sr  >> 1)) & 3;
  int sgk2 = (skq - (sr2 >> 1)) & 3;
  const unsigned short* gA0 = X + (long)(m0 + sr ) * DIM + sgk  * 8;
  const unsigned short* gA1 = X + (long)(m0 + sr2) * DIM + sgk2 * 8;
  const unsigned short* gB0 = W + (long)(n0 + sr ) * DIM + sgk  * 8;
  const unsigned short* gB1 = W + (long)(n0 + sr2) * DIM + sgk2 * 8;
  unsigned short* lA0 = As + sr  * BK + skq * 8;
  unsigned short* lA1 = As + sr2 * BK + skq * 8;
  unsigned short* lB0 = Bs + sr  * BK + skq * 8;
  unsigned short* lB1 = Bs + sr2 * BK + skq * 8;

  f32x4 acc[4][4];
  #pragma unroll
  for (int mt = 0; mt < 4; ++mt)
    #pragma unroll
    for (int nt = 0; nt < 4; ++nt) acc[mt][nt] = (f32x4){};

  short8 va0 = *(const short8*)(gA0);
  short8 va1 = *(const short8*)(gA1);
  short8 vb0 = *(const short8*)(gB0);
  short8 vb1 = *(const short8*)(gB1);

  int fr = l & 15, fk = l >> 4;
  for (int kt = 0; kt < DIM / BK; ++kt) {
    __syncthreads();
    *(short8*)lA0 = va0; *(short8*)lA1 = va1;
    *(short8*)lB0 = vb0; *(short8*)lB1 = vb1;
    __syncthreads();
    if (kt + 1 < DIM / BK) {
      int ko = (kt + 1) * BK;
      va0 = *(const short8*)(gA0 + ko);
      va1 = *(const short8*)(gA1 + ko);
      vb0 = *(const short8*)(gB0 + ko);
      vb1 = *(const short8*)(gB1 + ko);
    }
    short8 af[4], bf[4];
    #pragma unroll
    for (int mt = 0; mt < 4; ++mt) {
      int r = wr * 64 + mt * 16 + fr;
      int slot = ((r >> 1) + fk) & 3;
      af[mt] = *(const short8*)(As + r * BK + slot * 8);
    }
    #pragma unroll
    for (int nt = 0; nt < 4; ++nt) {
      int r = wc * 64 + nt * 16 + fr;
      int slot = ((r >> 1) + fk) & 3;
      bf[nt] = *(const short8*)(Bs + r * BK + slot * 8);
    }
    #pragma unroll
    for (int mt = 0; mt < 4; ++mt)
      #pragma unroll
      for (int nt = 0; nt < 4; ++nt)
        acc[mt][nt] = __builtin_amdgcn_mfma_f32_16x16x32_bf16(af[mt], bf[nt], acc[mt][nt], 0, 0, 0);
  }

  #pragma unroll
  for (int nt = 0; nt < 4; ++nt) {
    int n = n0 + wc * 64 + nt * 16 + fr;
    float bias = bih[n];
    #pragma unroll
    for (int mt = 0; mt < 4; ++mt) {
      int mbase = m0 + wr * 64 + mt * 16 + fk * 4;
      #pragma unroll
      for (int r = 0; r < 4; ++r)
        out[(long)(mbase + r) * G3 + n] = acc[mt][nt][r] + bias;
    }
  }
}

// ---------------- persistent masked GRU — ring h + packed parity flags ----------------
// R10 structure (ring slots -> L2-cached sc0 h reads, write-only LDS reduce,
// 24-deep counted-vmcnt load pipeline). Change: flags are PACKED (4B stride,
// one 128B line per step-parity). One coalesced wave-load per poll iteration
// replaces 32 independent line reads -> 32x less IF poll traffic, so producer
// h-stores/flag-stores drain through an uncontended coherent point.
#define MF(a, b, c) __builtin_amdgcn_mfma_f32_16x16x32_bf16(a, b, c, 0, 0, 0)

#define ISSUE(ss, kk) do { \
  asm volatile("global_load_dwordx4 %0, %1, off offset:%2 sc0" \
               : "=v"(bv[ss][0]) : "v"(ad0), "i"((kk) * 64) : "memory"); \
  asm volatile("global_load_dwordx4 %0, %1, off offset:%2 sc0" \
               : "=v"(bv[ss][1]) : "v"(ad1), "i"((kk) * 64) : "memory"); \
  asm volatile("global_load_dwordx4 %0, %1, off offset:%2 sc0" \
               : "=v"(bv[ss][2]) : "v"(ad2), "i"((kk) * 64) : "memory"); \
  asm volatile("global_load_dwordx4 %0, %1, off offset:%2 sc0" \
               : "=v"(bv[ss][3]) : "v"(ad3), "i"((kk) * 64) : "memory"); \
} while (0)

#define MF6(kk, ss, nt) \
  acc[0][nt] = MF(areg[0][kk], bv[ss][nt], acc[0][nt]); \
  acc[1][nt] = MF(areg[1][kk], bv[ss][nt], acc[1][nt]); \
  acc[2][nt] = MF(areg[2][kk], bv[ss][nt], acc[2][nt]); \
  acc[3][nt] = MF(areg[3][kk], bv[ss][nt], acc[3][nt]); \
  acc[4][nt] = MF(areg[4][kk], bv[ss][nt], acc[4][nt]); \
  acc[5][nt] = MF(areg[5][kk], bv[ss][nt], acc[5][nt]);

#define CONS(kk, ss, wn) do { \
  asm volatile("s_waitcnt vmcnt(" #wn ")" ::: "memory"); \
  __builtin_amdgcn_sched_barrier(0); \
  MF6(kk, ss, 0) MF6(kk, ss, 1) MF6(kk, ss, 2) MF6(kk, ss, 3) \
} while (0)

#define CONSI(kk, ss, wn, nk) do { CONS(kk, ss, wn); ISSUE(ss, nk); } while (0)

// arrive: h stores already issued; drain, block-sync, publish gen into the
// packed parity line (4B slot per block)
#define BARRIER_ARRIVE(tgtv) do { \
  asm volatile("s_waitcnt vmcnt(0)" ::: "memory"); \
  __syncthreads(); \
  if (tid == 0) { \
    unsigned fv_ = (unsigned)(tgtv); \
    uint64_t fa_ = (uint64_t)(bar + (((tgtv) & 1) << 5) + blockIdx.x); \
    asm volatile("global_store_dword %0, %1, off sc0 sc1" :: "v"(fa_), "v"(fv_) : "memory"); \
  } \
} while (0)

// wait: lanes 0..31 poll the packed line — ONE coalesced 128B transaction
// per iteration per block
#define BARRIER_WAIT(tgtv) do { \
  if (tid < NB) { \
    unsigned v_; \
    uint64_t pa_ = (uint64_t)(bar + (((tgtv) & 1) << 5) + tid); \
    do { \
      asm volatile("global_load_dword %0, %1, off sc0 sc1" : "=v"(v_) : "v"(pa_) : "memory"); \
      asm volatile("s_waitcnt vmcnt(0)" ::: "memory"); \
    } while (__any(v_ < (unsigned)(tgtv))); \
  } \
  __syncthreads(); \
} while (0)

__global__ __launch_bounds__(256, 1) void gru_kernel(
    const float* __restrict__ Whh, const float* __restrict__ bhh,
    const float* __restrict__ xw, const int* __restrict__ lengths,
    u64* __restrict__ hbf,            // ring: [RING][BATCH][HID/4] u64
    float* __restrict__ hf32,         // [BATCH][HID]
    unsigned int* __restrict__ bar, int T, int initzero)
{
  const int tid = threadIdx.x;
  const int w = tid >> 6, l = tid & 63;
  const int fr = l & 15, fk = l >> 4;
  const int U0 = blockIdx.x * HB;

  // ---- Whh fragments -> registers: wave w holds ALL 96 gate rows, K-quarter w*256..+255 ----
  short8 areg[6][8];
  #pragma unroll
  for (int mt = 0; mt < 6; ++mt) {
    const int m = mt * 16 + fr;                    // 0..95
    const int gate = m >> 5, u = m & 31;
    const float* wp = Whh + (size_t)(gate * HID + U0 + u) * HID + w * 256 + fk * 8;
    #pragma unroll
    for (int ksl = 0; ksl < 8; ++ksl) {
      f32x4 a0 = *(const f32x4*)(wp + ksl * 32);
      f32x4 a1 = *(const f32x4*)(wp + ksl * 32 + 4);
      areg[mt][ksl] = pack8(a0, a1);
    }
  }

  // ---- gate-phase ownership: batch gb = lane, units j0..j0+7 (j0 = wave*8) ----
  const int gb = l;
  const int j0 = w * 8;
  const size_t hoff = (size_t)gb * (HID / 4) + (size_t)(U0 + j0) / 4;  // u64 units within a slot
  const int len_b = lengths[gb];

  float h[8];
  #pragma unroll
  for (int j = 0; j < 8; ++j)
    h[j] = initzero ? 0.0f : hf32[(size_t)gb * HID + U0 + j0 + j];

  __shared__ float red2[4][64][100];   // 102.4 KB; [k-slice][batch][gate-row(+pad)]
  __shared__ float bb[3][32];          // biases for this block's 32 units x 3 gates
  if (tid < 96) bb[tid >> 5][tid & 31] = bhh[(tid >> 5) * HID + U0 + (tid & 31)];

  f32x4 xrv[2], xzv[2], xnv[2];
  #define LOAD_XW(tt) do { \
    const float* xp_ = xw + ((size_t)(tt) * BATCH + gb) * G3 + U0 + j0; \
    xrv[0] = *(const f32x4*)(xp_);            xrv[1] = *(const f32x4*)(xp_ + 4); \
    xzv[0] = *(const f32x4*)(xp_ + HID);      xzv[1] = *(const f32x4*)(xp_ + HID + 4); \
    xnv[0] = *(const f32x4*)(xp_ + 2 * HID);  xnv[1] = *(const f32x4*)(xp_ + 2 * HID + 4); \
  } while (0)

  // ---- publish h(0) into ring slot 0; entry inv drops stale ring lines ----
  {
    union { u64 q[2]; f32x4 v4; } pk;
    pk.q[0] = packbf4(h[0], h[1], h[2], h[3]);
    pk.q[1] = packbf4(h[4], h[5], h[6], h[7]);
    uint64_t hw = (uint64_t)(hbf + hoff);
    asm volatile("global_store_dwordx4 %0, %1, off sc0 sc1" :: "v"(hw), "v"(pk.v4) : "memory");
    BARRIER_ARRIVE(1);
    asm volatile("buffer_inv sc1" ::: "memory");
    LOAD_XW(0);
    BARRIER_WAIT(1);
  }

  for (int t = 0; t < T; ++t) {
    // drain xw prefetch / poll loads before manual vmcnt counting
    asm volatile("s_waitcnt vmcnt(0)" ::: "memory");

    const char* hbase = (const char*)hbf + (size_t)(t & (RING - 1)) * SLOT;
    // lane reads batch row (nt*16+fr), bytes [w*512 + ksl*64 + fk*16 .. +16)
    uint64_t ad0 = (uint64_t)(hbase + (size_t)(fr) * 2048 + w * 512 + fk * 16);
    uint64_t ad1 = ad0 + 16 * 2048;
    uint64_t ad2 = ad0 + 32 * 2048;
    uint64_t ad3 = ad0 + 48 * 2048;

    f32x4 acc[6][4];
    #pragma unroll
    for (int mt = 0; mt < 6; ++mt)
      #pragma unroll
      for (int nt = 0; nt < 4; ++nt) acc[mt][nt] = (f32x4){};

    short8 bv[6][4];
    ISSUE(0, 0); ISSUE(1, 1); ISSUE(2, 2); ISSUE(3, 3); ISSUE(4, 4); ISSUE(5, 5);
    CONSI(0, 0, 20, 6);
    CONSI(1, 1, 20, 7);
    CONS(2, 2, 20);
    CONS(3, 3, 16);
    CONS(4, 4, 12);
    CONS(5, 5, 8);
    CONS(6, 0, 4);
    CONS(7, 1, 0);

    // per-wave K-slice -> LDS, write-only, vectorized
    #pragma unroll
    for (int mt = 0; mt < 6; ++mt)
      #pragma unroll
      for (int nt = 0; nt < 4; ++nt)
        *(f32x4*)&red2[w][nt * 16 + fr][mt * 16 + fk * 4] = acc[mt][nt];
    __syncthreads();

    // gates: sum 4 K-slices (vector LDS reads), add bias, update h
    #define RD4(s, row) (*(const f32x4*)&red2[s][gb][row])
    f32x4 sr_[2], sz_[2], sn_[2];
    #pragma unroll
    for (int hh = 0; hh < 2; ++hh) {
      const int rbase = j0 + hh * 4;
      sr_[hh] = RD4(0, rbase)      + RD4(1, rbase)      + RD4(2, rbase)      + RD4(3, rbase)      + *(const f32x4*)&bb[0][rbase];
      sz_[hh] = RD4(0, 32 + rbase) + RD4(1, 32 + rbase) + RD4(2, 32 + rbase) + RD4(3, 32 + rbase) + *(const f32x4*)&bb[1][rbase];
      sn_[hh] = RD4(0, 64 + rbase) + RD4(1, 64 + rbase) + RD4(2, 64 + rbase) + RD4(3, 64 + rbase) + *(const f32x4*)&bb[2][rbase];
    }

    const int upd = (t < len_b);
    #pragma unroll
    for (int j = 0; j < 8; ++j) {
      float rr = sigm(xrv[j >> 2][j & 3] + sr_[j >> 2][j & 3]);
      float zz = sigm(xzv[j >> 2][j & 3] + sz_[j >> 2][j & 3]);
      float nn = tanh_fast(xnv[j >> 2][j & 3] + rr * sn_[j >> 2][j & 3]);
      float cc = (1.0f - zz) * nn + zz * h[j];
      h[j] = upd ? cc : h[j];
    }

    if (t + 1 < T) {
      union { u64 q[2]; f32x4 v4; } pk;
      pk.q[0] = packbf4(h[0], h[1], h[2], h[3]);
      pk.q[1] = packbf4(h[4], h[5], h[6], h[7]);
      uint64_t hw = (uint64_t)((char*)hbf + (size_t)((t + 1) & (RING - 1)) * SLOT + hoff * 8);
      asm volatile("global_store_dwordx4 %0, %1, off sc0 sc1" :: "v"(hw), "v"(pk.v4) : "memory");
      BARRIER_ARRIVE(t + 2);
      LOAD_XW(t + 1);   // prefetch next step's gate inputs under the barrier wait
      BARRIER_WAIT(t + 2);
      if (((t + 1) & (RING - 1)) == 0)               // ring wrap: drop this XCD's
        asm volatile("buffer_inv sc1" ::: "memory"); // 32-step-old ring lines
    }
  }

  #pragma unroll
  for (int j = 0; j < 8; ++j)
    hf32[(size_t)gb * HID + U0 + j0 + j] = h[j];
}

// ---------------- head: logits = tanh(h @ p1^T + b1) @ p2^T + b2 ----------------
__global__ __launch_bounds__(256) void head_kernel(
    const float* __restrict__ hf32, const float* __restrict__ p1W,
    const float* __restrict__ p1b, const float* __restrict__ p2W,
    const float* __restrict__ p2b, float* __restrict__ outp)
{
  int b = blockIdx.x;
  int tid = threadIdx.x;
  __shared__ float hrow[HID];
  __shared__ float red[4][64];
  __shared__ float s1[64];
  for (int d = tid; d < HID; d += 256) hrow[d] = hf32[(long)b * HID + d];
  __syncthreads();
  int j = tid & 63, q = tid >> 6;
  const float* wrow = p1W + (long)j * HID + q * 256;
  float s = 0.0f;
  for (int k = 0; k < 256; ++k) s += hrow[q * 256 + k] * wrow[k];
  red[q][j] = s;
  __syncthreads();
  if (tid < 64) {
    float v = red[0][tid] + red[1][tid] + red[2][tid] + red[3][tid] + p1b[tid];
    s1[tid] = tanh_fast(v);
  }
  __syncthreads();
  if (tid < 2) {
    float a = p2b[tid];
    for (int k = 0; k < 64; ++k) a += s1[k] * p2W[tid * 64 + k];
    outp[b * 2 + tid] = a;
  }
}

// ---------------- launch ----------------
extern "C" void kernel_launch(void* const* d_in, const int* in_sizes, int n_in,
                              void* d_out, int out_size, void* d_ws, size_t ws_size,
                              hipStream_t stream) {
  const int*   tgt_ids = (const int*)d_in[0];
  const int*   tgt_len = (const int*)d_in[1];
  const int*   src_ids = (const int*)d_in[2];
  const int*   src_len = (const int*)d_in[3];
  const float* emb  = (const float*)d_in[6];
  const float* sWih = (const float*)d_in[7];
  const float* sWhh = (const float*)d_in[8];
  const float* sbih = (const float*)d_in[9];
  const float* sbhh = (const float*)d_in[10];
  const float* tWih = (const float*)d_in[11];
  const float* tWhh = (const float*)d_in[12];
  const float* tbih = (const float*)d_in[13];
  const float* tbhh = (const float*)d_in[14];
  const float* p1W  = (const float*)d_in[19];
  const float* p1b  = (const float*)d_in[20];
  const float* p2W  = (const float*)d_in[21];
  const float* p2b  = (const float*)d_in[22];

  char* ws = (char*)d_ws;
  size_t off = 0;
  float* xw = (float*)(ws + off);                   off += (size_t)MROWS * G3 * 4;   // 100.7 MB
  unsigned short* X  = (unsigned short*)(ws + off); off += (size_t)MROWS * DIM * 2;  // 8.4 MB
  unsigned short* Wb = (unsigned short*)(ws + off); off += (size_t)G3 * DIM * 2;     // 3.1 MB
  float* hf32 = (float*)(ws + off);                 off += (size_t)BATCH * HID * 4;
  unsigned int* bars = (unsigned int*)(ws + off);   off += 8192;
  if (ws_size < off) return;
  // h ring (4.2 MB) aliases the X/Wb staging region (11.5 MB): X/Wb live only
  // between prep and xw_gemm; the ring lives only inside gru_kernel; each
  // gru's entry buffer_inv drops stale cached lines from the prior use.
  u64* hbf = (u64*)X;

  const int PREP_BLOCKS = MROWS + G3;  // 11264

  // src pipeline
  prep_kernel<<<PREP_BLOCKS, 256, 0, stream>>>(src_ids, emb, sWih, X, Wb, bars);
  xw_gemm<<<dim3(G3 / BN, MROWS / BM), 256, 0, stream>>>(X, Wb, sbih, xw);
  gru_kernel<<<NB, 256, 0, stream>>>(sWhh, sbhh, xw, src_len, hbf, hf32, bars, TSEQ, 1);
  // tgt pipeline (h0 = src final hidden in hf32)
  prep_kernel<<<PREP_BLOCKS, 256, 0, stream>>>(tgt_ids, emb, tWih, X, Wb, nullptr);
  xw_gemm<<<dim3(G3 / BN, MROWS / BM), 256, 0, stream>>>(X, Wb, tbih, xw);
  gru_kernel<<<NB, 256, 0, stream>>>(tWhh, tbhh, xw, tgt_len, hbf, hf32, bars + 1024, TSEQ, 0);
  // head
  head_kernel<<<BATCH, 256, 0, stream>>>(hf32, p1W, p1b, p2W, p2b, (float*)d_out);
}